// Round 2
// baseline (82.935 us; speedup 1.0000x reference)
//
#include <hip/hip_runtime.h>

// NEUROPULS unitary mesh, N=256 — R6: CORRECTED stage-collapse + DPP crossing.
// R5 post-mortem: algebra bug. mmi2*diag(p0,p1)*mmi2 does NOT factorize per
// phase; the correct collapsed pair operator is
//   [[ U*p0 - W*p1 ,  i*g*(p0+p1) ],
//    [ i*g*(p0+p1) ,  U*p1 - W*p0 ]]
// with U = AT^2 = 0.98*0.505, W = AR^2 = 0.98*0.495, g = AT*AR.
// Coefficients E = U*p0-W*p1, F = U*p1-W*p0, G = i*g*(p0+p1) are theta-only
// -> prepped one stage ahead, off the serial chain.
// Crossing +-1 lane exchange via DPP wave_shr:1 / wave_shl:1 (VALU pipe,
// ~8cy) instead of ds_bpermute (~60cy); edge lanes masked by thru selects.

__device__ __forceinline__ float dpp_up1(float x) {
    // lane n <- lane n-1 (wave_shr:1); lane 0 keeps old (=x), masked later
    return __int_as_float(__builtin_amdgcn_update_dpp(
        __float_as_int(x), __float_as_int(x), 0x138, 0xf, 0xf, false));
}
__device__ __forceinline__ float dpp_dn1(float x) {
    // lane n <- lane n+1 (wave_shl:1); lane 63 keeps old (=x), masked later
    return __int_as_float(__builtin_amdgcn_update_dpp(
        __float_as_int(x), __float_as_int(x), 0x130, 0xf, 0xf, false));
}

__device__ __forceinline__ void sincos4(float4 th, float sn[4], float cs[4]) {
    __sincosf(th.x, &sn[0], &cs[0]);
    __sincosf(th.y, &sn[1], &cs[1]);
    __sincosf(th.z, &sn[2], &cs[2]);
    __sincosf(th.w, &sn[3], &cs[3]);
}

// Per-stage collapsed-operator coefficients, 2 pairs per lane:
// E[p], F[p], G[p] complex -> 12 floats.
struct Coef {
    float Er[2], Ei[2], Fr[2], Fi[2], Gr[2], Gi[2];
};

__global__ __launch_bounds__(64)
void neuropuls_mesh_kernel(const float* __restrict__ thetas,  // [130,256] fp32
                           float* __restrict__ out)           // re[65536] || im[65536]
{
    constexpr int N = 256;
    const int lane = threadIdx.x;   // 0..63
    const int col  = blockIdx.x;    // 0..255

    const float U  = 0.98f * 0.505f;                  // AT^2
    const float W  = 0.98f * 0.495f;                  // AR^2
    const float Gc = 0.98f * sqrtf(0.505f * 0.495f);  // AT*AR
    const float BT = sqrtf(0.98f * 0.01f);            // CR a*sqrt(CT)
    const float BR = sqrtf(0.98f * 0.99f);            // CR a*sqrt(1-CT) == thru

    float vr[4] = {0.f, 0.f, 0.f, 0.f};
    float vi[4] = {0.f, 0.f, 0.f, 0.f};

    // arch0 = diag(exp(i*theta[0]))
    {
        const float th0 = thetas[col];
        float s0, c0;
        __sincosf(th0, &s0, &c0);
        const int r0 = col - 4 * lane;
        if (0 <= r0 && r0 < 4) { vr[r0] = c0; vi[r0] = s0; }
    }

    const float* tp = thetas + N + 4 * lane;   // theta[s][4*lane..], s from 1

    auto prep4 = [&](float4 th, Coef& K) {
        float s[4], c[4];
        sincos4(th, s, c);
        #pragma unroll
        for (int p = 0; p < 2; ++p) {
            const float c0 = c[2 * p], c1 = c[2 * p + 1];
            const float s0 = s[2 * p], s1 = s[2 * p + 1];
            K.Er[p] = U * c0 - W * c1;   K.Ei[p] = U * s0 - W * s1;
            K.Fr[p] = U * c1 - W * c0;   K.Fi[p] = U * s1 - W * s0;
            K.Gr[p] = -Gc * (s0 + s1);   K.Gi[p] = Gc * (c0 + c1);
        }
    };

    // Collapsed MMI*diag(p)*MMI on pairs (0,1),(2,3):
    //   x' = E*x + G*y ;  y' = G*x + F*y   (complex)
    auto mstep = [&](const Coef& K) {
        #pragma unroll
        for (int p = 0; p < 2; ++p) {
            const int x = 2 * p, y = 2 * p + 1;
            const float xr = vr[x], xi = vi[x], yr = vr[y], yi = vi[y];
            vr[x] = K.Er[p] * xr - K.Ei[p] * xi + K.Gr[p] * yr - K.Gi[p] * yi;
            vi[x] = K.Er[p] * xi + K.Ei[p] * xr + K.Gr[p] * yi + K.Gi[p] * yr;
            vr[y] = K.Gr[p] * xr - K.Gi[p] * xi + K.Fr[p] * yr - K.Fi[p] * yi;
            vi[y] = K.Gr[p] * xi + K.Gi[p] * xr + K.Fr[p] * yi + K.Fi[p] * yr;
        }
    };

    auto crossing = [&]() {
        float pv3r = dpp_up1(vr[3]);
        float pv3i = dpp_up1(vi[3]);
        float nv0r = dpp_dn1(vr[0]);
        float nv0i = dpp_dn1(vi[0]);
        {   // internal odd pair (4t+1, 4t+2)
            float xr = vr[1], xi = vi[1], yr = vr[2], yi = vi[2];
            vr[1] = BT * xr - BR * yi;  vi[1] = BT * xi + BR * yr;
            vr[2] = BT * yr - BR * xi;  vi[2] = BT * yi + BR * xr;
        }
        {   // pair (4t-1, 4t): lane 0 row 0 = thru
            float yr = vr[0], yi = vi[0];
            float nr = BT * yr - BR * pv3i;
            float ni = BT * yi + BR * pv3r;
            vr[0] = (lane == 0) ? BR * yr : nr;
            vi[0] = (lane == 0) ? BR * yi : ni;
        }
        {   // pair (4t+3, 4t+4): lane 63 row 255 = thru
            float xr = vr[3], xi = vi[3];
            float nr = BT * xr - BR * nv0i;
            float ni = BT * xi + BR * nv0r;
            vr[3] = (lane == 63) ? BR * xr : nr;
            vi[3] = (lane == 63) ? BR * xi : ni;
        }
    };

    // ---- software pipeline ----
    // invariant entering iter s: KA = coeffs(theta[s]); thB = theta[s+1];
    // thC = theta[s+2]; tp -> theta[s+3].
    Coef KA;
    float4 thB, thC;
    {
        float4 t1 = *(const float4*)tp;  tp += N;   // theta[1]
        thB       = *(const float4*)tp;  tp += N;   // theta[2]
        thC       = *(const float4*)tp;  tp += N;   // theta[3]
        prep4(t1, KA);
    }

    // crossing stages s = 1..126 (127th handled after the loop)
    #pragma unroll 2
    for (int s = 1; s <= 126; ++s) {
        float4 thD = *(const float4*)tp;  tp += N;  // theta[s+3] (<=129) in flight
        Coef KB;
        prep4(thB, KB);                             // coeffs for stage s+1, off-chain
        // ---- serial state chain: one collapsed matvec + crossing ----
        mstep(KA);
        crossing();
        // rotate pipeline regs (copy-prop'd away under unroll 2)
        KA = KB;
        thB = thC; thC = thD;
    }

    // stage s = 127 (last crossing stage); KA = coeffs(theta[127])
    mstep(KA);
    crossing();

    // stage s = 128: MMI*diag(theta[128])*MMI, no crossing; then phase(theta[129])
    {
        Coef KF;
        prep4(thB, KF);                             // thB = theta[128]
        mstep(KF);
        float sn[4], cs[4];
        sincos4(thC, sn, cs);                       // thC = theta[129]
        #pragma unroll
        for (int j = 0; j < 4; ++j) {
            float r = vr[j], i = vi[j];
            vr[j] = cs[j] * r - sn[j] * i;
            vi[j] = cs[j] * i + sn[j] * r;
        }
    }

    // store PLANAR: real block then imag block, each row-major [row][col]
    #pragma unroll
    for (int j = 0; j < 4; ++j) {
        const int idx = (4 * lane + j) * N + col;
        out[idx]         = vr[j];
        out[N * N + idx] = vi[j];
    }
}

extern "C" void kernel_launch(void* const* d_in, const int* in_sizes, int n_in,
                              void* d_out, int out_size, void* d_ws, size_t ws_size,
                              hipStream_t stream)
{
    const float* thetas = (const float*)d_in[0];   // [130,256] fp32
    float* out = (float*)d_out;                    // planar: re[65536] || im[65536]
    (void)in_sizes; (void)n_in; (void)out_size; (void)d_ws; (void)ws_size;
    neuropuls_mesh_kernel<<<dim3(256), dim3(64), 0, stream>>>(thetas, out);
}

// Round 4
// 80.058 us; speedup vs baseline: 1.0359x; 1.0359x over previous
//
#include <hip/hip_runtime.h>

// NEUROPULS unitary mesh, N=256 — R7 (resubmit; R3 bench was an infra
// failure, no signal): unlock VGPR budget so the pipeline actually
// pipelines.
// R6 post-mortem: VGPR_Count=32 — the compiler scheduled for 8-wave
// occupancy and re-serialized the software pipeline (load+sincos+prep sunk
// onto the serial chain), so stage-collapse bought nothing (~750 cy/stage,
// VALUBusy 12% of a 25% single-SIMD ceiling). Occupancy is irrelevant here:
// grid = 256 blocks x 1 wave on 256 CUs, 1 wave/CU no matter what.
// Fix: __launch_bounds__(64, 1) -> min 1 wave/EU -> VGPR cap ~max, letting
// the scheduler keep 3-deep theta prefetch + 1-stage-ahead coeff prep live.
// Serial chain left: mstep (depth-4 FMA) + crossing (DPP + depth-2).
// Unroll 3 (126 = 42*3) so the 3-deep theta rotation renames away.

__device__ __forceinline__ float dpp_up1(float x) {
    // lane n <- lane n-1 (wave_shr:1); lane 0 keeps old (=x), masked later
    return __int_as_float(__builtin_amdgcn_update_dpp(
        __float_as_int(x), __float_as_int(x), 0x138, 0xf, 0xf, false));
}
__device__ __forceinline__ float dpp_dn1(float x) {
    // lane n <- lane n+1 (wave_shl:1); lane 63 keeps old (=x), masked later
    return __int_as_float(__builtin_amdgcn_update_dpp(
        __float_as_int(x), __float_as_int(x), 0x130, 0xf, 0xf, false));
}

__device__ __forceinline__ void sincos4(float4 th, float sn[4], float cs[4]) {
    __sincosf(th.x, &sn[0], &cs[0]);
    __sincosf(th.y, &sn[1], &cs[1]);
    __sincosf(th.z, &sn[2], &cs[2]);
    __sincosf(th.w, &sn[3], &cs[3]);
}

// Per-stage collapsed-operator coefficients, 2 pairs per lane:
// E[p], F[p], G[p] complex -> 12 floats.
struct Coef {
    float Er[2], Ei[2], Fr[2], Fi[2], Gr[2], Gi[2];
};

__global__ __launch_bounds__(64, 1)
void neuropuls_mesh_kernel(const float* __restrict__ thetas,  // [130,256] fp32
                           float* __restrict__ out)           // re[65536] || im[65536]
{
    constexpr int N = 256;
    const int lane = threadIdx.x;   // 0..63
    const int col  = blockIdx.x;    // 0..255

    const float U  = 0.98f * 0.505f;                  // AT^2
    const float W  = 0.98f * 0.495f;                  // AR^2
    const float Gc = 0.98f * sqrtf(0.505f * 0.495f);  // AT*AR
    const float BT = sqrtf(0.98f * 0.01f);            // CR a*sqrt(CT)
    const float BR = sqrtf(0.98f * 0.99f);            // CR a*sqrt(1-CT) == thru

    float vr[4] = {0.f, 0.f, 0.f, 0.f};
    float vi[4] = {0.f, 0.f, 0.f, 0.f};

    // arch0 = diag(exp(i*theta[0]))
    {
        const float th0 = thetas[col];
        float s0, c0;
        __sincosf(th0, &s0, &c0);
        const int r0 = col - 4 * lane;
        if (0 <= r0 && r0 < 4) { vr[r0] = c0; vi[r0] = s0; }
    }

    const float* tp = thetas + N + 4 * lane;   // theta[s][4*lane..], s from 1

    auto prep4 = [&](float4 th, Coef& K) {
        float s[4], c[4];
        sincos4(th, s, c);
        #pragma unroll
        for (int p = 0; p < 2; ++p) {
            const float c0 = c[2 * p], c1 = c[2 * p + 1];
            const float s0 = s[2 * p], s1 = s[2 * p + 1];
            K.Er[p] = U * c0 - W * c1;   K.Ei[p] = U * s0 - W * s1;
            K.Fr[p] = U * c1 - W * c0;   K.Fi[p] = U * s1 - W * s0;
            K.Gr[p] = -Gc * (s0 + s1);   K.Gi[p] = Gc * (c0 + c1);
        }
    };

    // Collapsed MMI*diag(p)*MMI on pairs (0,1),(2,3):
    //   x' = E*x + G*y ;  y' = G*x + F*y   (complex)
    auto mstep = [&](const Coef& K) {
        #pragma unroll
        for (int p = 0; p < 2; ++p) {
            const int x = 2 * p, y = 2 * p + 1;
            const float xr = vr[x], xi = vi[x], yr = vr[y], yi = vi[y];
            vr[x] = K.Er[p] * xr - K.Ei[p] * xi + K.Gr[p] * yr - K.Gi[p] * yi;
            vi[x] = K.Er[p] * xi + K.Ei[p] * xr + K.Gr[p] * yi + K.Gi[p] * yr;
            vr[y] = K.Gr[p] * xr - K.Gi[p] * xi + K.Fr[p] * yr - K.Fi[p] * yi;
            vi[y] = K.Gr[p] * xi + K.Gi[p] * xr + K.Fr[p] * yi + K.Fi[p] * yr;
        }
    };

    auto crossing = [&]() {
        float pv3r = dpp_up1(vr[3]);
        float pv3i = dpp_up1(vi[3]);
        float nv0r = dpp_dn1(vr[0]);
        float nv0i = dpp_dn1(vi[0]);
        {   // internal odd pair (4t+1, 4t+2)
            float xr = vr[1], xi = vi[1], yr = vr[2], yi = vi[2];
            vr[1] = BT * xr - BR * yi;  vi[1] = BT * xi + BR * yr;
            vr[2] = BT * yr - BR * xi;  vi[2] = BT * yi + BR * xr;
        }
        {   // pair (4t-1, 4t): lane 0 row 0 = thru
            float yr = vr[0], yi = vi[0];
            float nr = BT * yr - BR * pv3i;
            float ni = BT * yi + BR * pv3r;
            vr[0] = (lane == 0) ? BR * yr : nr;
            vi[0] = (lane == 0) ? BR * yi : ni;
        }
        {   // pair (4t+3, 4t+4): lane 63 row 255 = thru
            float xr = vr[3], xi = vi[3];
            float nr = BT * xr - BR * nv0i;
            float ni = BT * xi + BR * nv0r;
            vr[3] = (lane == 63) ? BR * xr : nr;
            vi[3] = (lane == 63) ? BR * xi : ni;
        }
    };

    // ---- software pipeline ----
    // invariant entering iter s: KA = coeffs(theta[s]); thB = theta[s+1];
    // thC = theta[s+2]; tp -> theta[s+3].
    Coef KA;
    float4 thB, thC;
    {
        float4 t1 = *(const float4*)tp;  tp += N;   // theta[1]
        thB       = *(const float4*)tp;  tp += N;   // theta[2]
        thC       = *(const float4*)tp;  tp += N;   // theta[3]
        prep4(t1, KA);
    }

    // crossing stages s = 1..126 (127th handled after the loop); 126 = 42*3
    #pragma unroll 3
    for (int s = 1; s <= 126; ++s) {
        float4 thD = *(const float4*)tp;  tp += N;  // theta[s+3] (<=129) in flight
        Coef KB;
        prep4(thB, KB);                             // coeffs for stage s+1, off-chain
        // ---- serial state chain: one collapsed matvec + crossing ----
        mstep(KA);
        crossing();
        // rotate pipeline regs (renamed away by unroll + SSA copy-prop)
        KA = KB;
        thB = thC; thC = thD;
    }

    // stage s = 127 (last crossing stage); KA = coeffs(theta[127])
    mstep(KA);
    crossing();

    // stage s = 128: MMI*diag(theta[128])*MMI, no crossing; then phase(theta[129])
    {
        Coef KF;
        prep4(thB, KF);                             // thB = theta[128]
        mstep(KF);
        float sn[4], cs[4];
        sincos4(thC, sn, cs);                       // thC = theta[129]
        #pragma unroll
        for (int j = 0; j < 4; ++j) {
            float r = vr[j], i = vi[j];
            vr[j] = cs[j] * r - sn[j] * i;
            vi[j] = cs[j] * i + sn[j] * r;
        }
    }

    // store PLANAR: real block then imag block, each row-major [row][col]
    #pragma unroll
    for (int j = 0; j < 4; ++j) {
        const int idx = (4 * lane + j) * N + col;
        out[idx]         = vr[j];
        out[N * N + idx] = vi[j];
    }
}

extern "C" void kernel_launch(void* const* d_in, const int* in_sizes, int n_in,
                              void* d_out, int out_size, void* d_ws, size_t ws_size,
                              hipStream_t stream)
{
    const float* thetas = (const float*)d_in[0];   // [130,256] fp32
    float* out = (float*)d_out;                    // planar: re[65536] || im[65536]
    (void)in_sizes; (void)n_in; (void)out_size; (void)d_ws; (void)ws_size;
    neuropuls_mesh_kernel<<<dim3(256), dim3(64), 0, stream>>>(thetas, out);
}